// Round 14
// baseline (444.781 us; speedup 1.0000x reference)
//
#include <hip/hip_runtime.h>
#include <hip/hip_bf16.h>
#include <cmath>

typedef __bf16 bf16_t;
typedef __bf16 bf16x8 __attribute__((ext_vector_type(8)));
typedef float f32x4 __attribute__((ext_vector_type(4)));
typedef float f32x16 __attribute__((ext_vector_type(16)));
typedef unsigned short u16;
typedef unsigned int u32;
typedef unsigned int u32x2 __attribute__((ext_vector_type(2)));

// fast exp: raw v_exp_f32 (exp2 domain) when available, else __expf (natural)
#if defined(__has_builtin)
#if __has_builtin(__builtin_amdgcn_exp2f)
#define ATTN_EXP(x) __builtin_amdgcn_exp2f(x)
#define ATTN_LOG2E 1.4426950408889634f
#define HAVE_EXP2 1
#endif
#if __has_builtin(__builtin_amdgcn_permlane32_swap)
#define HAVE_PL32 1
#endif
#if __has_builtin(__builtin_amdgcn_rcpf)
#define FAST_RCP(x) __builtin_amdgcn_rcpf(x)
#endif
#endif
#ifndef ATTN_EXP
#define ATTN_EXP(x) __expf(x)
#define ATTN_LOG2E 1.0f
#endif
#ifndef FAST_RCP
#define FAST_RCP(x) (1.0f / (x))
#endif

// fast GELU, tanh form via exp2-sigmoid (~8 VALU vs ~25-30 for erff;
// |err| ~1e-3, below bf16 output quantization; h1 is LayerNorm'd after).
__device__ __forceinline__ float fast_gelu(float v) {
#ifdef HAVE_EXP2
  float u = v * __builtin_fmaf(0.044715f, v * v, 1.0f);
  float z = __builtin_amdgcn_exp2f(-2.3022163968f * u);
  return v * FAST_RCP(1.0f + z);
#else
  return 0.5f * v * (1.0f + erff(v * 0.70710678118654752f));
#endif
}

// ---------------- async global->LDS (16B per lane) ----------------
__device__ __forceinline__ void load16(const bf16_t* g, bf16_t* l) {
  __builtin_amdgcn_global_load_lds((const __attribute__((address_space(1))) u32*)g,
                                   (__attribute__((address_space(3))) u32*)l, 16, 0, 0);
}

__device__ __forceinline__ u32 pk2(float a, float b) {
  bf16_t x = (bf16_t)a, y = (bf16_t)b;
  u16 ux = __builtin_bit_cast(u16, x), uy = __builtin_bit_cast(u16, y);
  return (u32)ux | ((u32)uy << 16);
}

union V4U { u32 w[4]; bf16x8 v; };

// cross-half (lane^32) exchange of two values in ONE VALU op (T12/m255).
__device__ __forceinline__ void pl32(u32 a, u32 b, u32& out_lo, u32& out_hi) {
#ifdef HAVE_PL32
  u32x2 r = __builtin_amdgcn_permlane32_swap(a, b, false, false);
  out_lo = r[0];
  out_hi = r[1];
#else
  u32 ax = (u32)__shfl_xor((int)a, 32), bx = (u32)__shfl_xor((int)b, 32);
  out_lo = (threadIdx.x & 32) ? bx : a;
  out_hi = (threadIdx.x & 32) ? b : ax;
#endif
}

__device__ __forceinline__ float pl32_sum(float x) {
  u32 lo, hi;
  pl32(__builtin_bit_cast(u32, x), __builtin_bit_cast(u32, x), lo, hi);
  return __builtin_bit_cast(float, lo) + __builtin_bit_cast(float, hi);
}

// ---------------- fused prep: weight transposes (64x64, float4) + rope ----------------
__device__ __forceinline__ void tr64(const float* __restrict__ src, bf16_t* __restrict__ dst,
                                     int Kd, int Nd, int ntile, int ktile, int tid) {
  __shared__ float tile[64][68];
  int n0 = ntile * 64, k0 = ktile * 64;
  int r = tid >> 2, c4 = (tid & 3) * 4;
  const float* sp = src + (size_t)(k0 + r) * Nd + n0;
#pragma unroll
  for (int c = 0; c < 4; ++c)
    *(float4*)&tile[r][c * 16 + c4] = *(const float4*)(sp + c * 16 + c4);
  __syncthreads();
  int n = tid >> 2;
  bf16_t* dp = dst + (size_t)(n0 + n) * Kd + k0;
#pragma unroll
  for (int c = 0; c < 4; ++c) {
    int kk = c * 16 + c4;
    uint2 pk;
    pk.x = pk2(tile[kk + 0][n], tile[kk + 1][n]);
    pk.y = pk2(tile[kk + 2][n], tile[kk + 3][n]);
    *(uint2*)(dp + kk) = pk;
  }
}

__global__ __launch_bounds__(256) void prep_kernel(
    const float* __restrict__ qkv_w, const float* __restrict__ proj_w,
    const float* __restrict__ fc1_w, const float* __restrict__ fc2_w,
    bf16_t* __restrict__ qkvT, bf16_t* __restrict__ projT,
    bf16_t* __restrict__ fc1T, bf16_t* __restrict__ fc2T,
    float* __restrict__ ropeC, float* __restrict__ ropeS) {
  int b = blockIdx.x, tid = threadIdx.x;
  if (b < 768) {
    tr64(qkv_w, qkvT, 1024, 3072, b % 48, b / 48, tid);
  } else if (b < 1024) {
    int r = b - 768; tr64(proj_w, projT, 1024, 1024, r % 16, r / 16, tid);
  } else if (b < 2048) {
    int r = b - 1024; tr64(fc1_w, fc1T, 1024, 4096, r % 64, r / 64, tid);
  } else if (b < 3072) {
    int r = b - 2048; tr64(fc2_w, fc2T, 4096, 1024, r % 16, r / 16, tid);
  } else {
    int idx = (b - 3072) * 256 + tid;
    int pos = idx >> 5, t = idx & 31;
    float e = (float)(2 * t) / 64.0f;
    float inv = powf(10000.0f, -e);
    float a = (float)pos * inv;
    ropeC[idx] = cosf(a);
    ropeS[idx] = sinf(a);
  }
}

// ---------------- LayerNorm: one row per block, width W, vectorized ----------------
template <typename TI, int W>
__global__ __launch_bounds__(256) void ln_kernel(const TI* __restrict__ in,
                                                 const float* __restrict__ g,
                                                 const float* __restrict__ b,
                                                 bf16_t* __restrict__ out) {
  constexpr int CH = (sizeof(TI) == 2) ? 8 : 4;   // 16B chunks
  constexpr int NS = W / (256 * CH);
  int row = blockIdx.x;
  const TI* p = in + (size_t)row * W;
  float vals[NS * CH];
  float s = 0.f, q = 0.f;
#pragma unroll
  for (int sw = 0; sw < NS; ++sw) {
    int base = sw * (256 * CH) + threadIdx.x * CH;
    if constexpr (sizeof(TI) == 2) {
      bf16x8 v = *(const bf16x8*)(p + base);
#pragma unroll
      for (int e = 0; e < 8; ++e) {
        float f = (float)v[e];
        vals[sw * CH + e] = f; s += f; q += f * f;
      }
    } else {
      float4 v = *(const float4*)(p + base);
      float f0 = v.x, f1 = v.y, f2 = v.z, f3 = v.w;
      vals[sw * CH + 0] = f0; vals[sw * CH + 1] = f1;
      vals[sw * CH + 2] = f2; vals[sw * CH + 3] = f3;
      s += (f0 + f1) + (f2 + f3);
      q += (f0 * f0 + f1 * f1) + (f2 * f2 + f3 * f3);
    }
  }
  for (int off = 32; off; off >>= 1) { s += __shfl_xor(s, off); q += __shfl_xor(q, off); }
  __shared__ float red[8];
  int wave = threadIdx.x >> 6, lane = threadIdx.x & 63;
  if (lane == 0) { red[wave] = s; red[4 + wave] = q; }
  __syncthreads();
  s = red[0] + red[1] + red[2] + red[3];
  q = red[4] + red[5] + red[6] + red[7];
  float mu = s * (1.0f / W);
  float var = q * (1.0f / W) - mu * mu;
  float rstd = rsqrtf(var + 1e-5f);
  bf16_t* op = out + (size_t)row * W;
#pragma unroll
  for (int sw = 0; sw < NS; ++sw) {
    int base = sw * (256 * CH) + threadIdx.x * CH;
    float o[CH];
#pragma unroll
    for (int e = 0; e < CH; ++e)
      o[e] = (vals[sw * CH + e] - mu) * rstd * g[base + e] + b[base + e];
    if constexpr (CH == 8) {
      V4U u;
      u.w[0] = pk2(o[0], o[1]); u.w[1] = pk2(o[2], o[3]);
      u.w[2] = pk2(o[4], o[5]); u.w[3] = pk2(o[6], o[7]);
      *(bf16x8*)(op + base) = u.v;
    } else {
      uint2 pk; pk.x = pk2(o[0], o[1]); pk.y = pk2(o[2], o[3]);
      *(uint2*)(op + base) = pk;
    }
  }
}

// ---------------- split-K combine: out = sum(partials) + resid + bias ----------------
template <int NS>
__global__ __launch_bounds__(256) void reduceN_kernel(
    const float* __restrict__ part, const float* __restrict__ resid,
    const float* __restrict__ bias, float* __restrict__ out) {
  const int total4 = (4096 * 1024) / 4;
  const float4* r4 = (const float4*)resid;
  const float4* b4 = (const float4*)bias;
  float4* o4 = (float4*)out;
  for (int i = blockIdx.x * 256 + threadIdx.x; i < total4; i += gridDim.x * 256) {
    float4 a = ((const float4*)part)[i];
#pragma unroll
    for (int s = 1; s < NS; ++s) {
      float4 p = ((const float4*)(part + (size_t)s * 4096 * 1024))[i];
      a.x += p.x; a.y += p.y; a.z += p.z; a.w += p.w;
    }
    float4 r = r4[i], bb = b4[i & 255];
    float4 o;
    o.x = a.x + (r.x + bb.x);
    o.y = a.y + (r.y + bb.y);
    o.z = a.z + (r.z + bb.z);
    o.w = a.w + (r.w + bb.w);
    o4[i] = o;
  }
}

// ---------------- GEMM: C[m][n] = sum_k A[m][k]*Bt[n][k] ----------------
enum { EPI_QKV = 0, EPI_RESID = 1, EPI_GELU = 2, EPI_PART = 3 };

template <int EPI, int TM>
__global__ __launch_bounds__(256, 2) void gemm_bt(
    const bf16_t* __restrict__ A, const bf16_t* __restrict__ Bt, int M, int Nn, int K,
    int gy, int ksteps,
    const float* __restrict__ bias, const float* __restrict__ resid,
    float* __restrict__ outf, bf16_t* __restrict__ outb,
    bf16_t* __restrict__ qb, bf16_t* __restrict__ kb, bf16_t* __restrict__ vtb,
    const float* __restrict__ ropeC, const float* __restrict__ ropeS) {
  constexpr int MT = TM / 32;                 // mfma m-tiles per wave
  __shared__ bf16_t lsA[2][TM * 32];
  __shared__ bf16_t lsB[2][128 * 32];
  const int tid = threadIdx.x;
  const int lane = tid & 63;
  const int wave = tid >> 6;
  const int l16 = lane & 15, quad = lane >> 4;
  const int wm = (wave >> 1) * (TM / 2), wn = (wave & 1) * 64;
  const int bb = blockIdx.x;
  const int m0 = (bb % gy) * TM, n0 = (bb / gy) * 128;
  const int kbase = blockIdx.y * (ksteps << 5);

  f32x4 acc[MT][4];
  for (int i = 0; i < MT; ++i)
    for (int j = 0; j < 4; ++j) acc[i][j] = {0.f, 0.f, 0.f, 0.f};

  auto stage = [&](int kk, int buf) {
    bf16_t* la = &lsA[buf][0];
    bf16_t* lb = &lsB[buf][0];
#pragma unroll
    for (int i = 0; i < TM / 64; ++i) {
      int s = tid + i * 256;
      int row = s >> 2, ch = (s & 3) ^ (row & 3);
      load16(A + (size_t)(m0 + row) * K + kk + ch * 8, la + s * 8);
    }
#pragma unroll
    for (int i = 0; i < 2; ++i) {
      int s = tid + i * 256;
      int row = s >> 2, ch = (s & 3) ^ (row & 3);
      load16(Bt + (size_t)(n0 + row) * K + kk + ch * 8, lb + s * 8);
    }
  };

  stage(kbase, 0);
  for (int ki = 0; ki < ksteps; ++ki) {
    __syncthreads();                        // buf[ki&1] ready
    if (ki + 1 < ksteps) stage(kbase + ((ki + 1) << 5), (ki + 1) & 1);
    const bf16_t* la = &lsA[ki & 1][0];
    const bf16_t* lb = &lsB[ki & 1][0];
    bf16x8 af[MT], bfr[4];
#pragma unroll
    for (int t = 0; t < MT; ++t) {
      int row = wm + t * 16 + l16;
      af[t] = *(const bf16x8*)(la + row * 32 + (quad ^ (row & 3)) * 8);
    }
#pragma unroll
    for (int t = 0; t < 4; ++t) {
      int row = wn + t * 16 + l16;
      bfr[t] = *(const bf16x8*)(lb + row * 32 + (quad ^ (row & 3)) * 8);
    }
#pragma unroll
    for (int mt = 0; mt < MT; ++mt)
#pragma unroll
      for (int nt = 0; nt < 4; ++nt)
        acc[mt][nt] = __builtin_amdgcn_mfma_f32_16x16x32_bf16(af[mt], bfr[nt], acc[mt][nt], 0, 0, 0);
  }

  // epilogue: row = m0+wm+mt*16+quad*4+r, col = n0+wn+nt*16+l16
  for (int mt = 0; mt < MT; ++mt) {
    for (int nt = 0; nt < 4; ++nt) {
      int gn = n0 + wn + nt * 16 + l16;
      int gm0 = m0 + wm + mt * 16 + quad * 4;
      if constexpr (EPI == EPI_QKV) {
        int which = gn >> 10;              // 0=q 1=k 2=v (uniform per nt)
        int hd = gn & 1023, head = hd >> 6, d = hd & 63;
        if (which == 2) {
          u32 lo, hi;
          {
            float v0 = acc[mt][nt][0] + bias[gn];
            float v1 = acc[mt][nt][1] + bias[gn];
            float v2 = acc[mt][nt][2] + bias[gn];
            float v3 = acc[mt][nt][3] + bias[gn];
            lo = pk2(v0, v1);
            hi = pk2(v2, v3);
          }
          int b = gm0 >> 11, pos = gm0 & 2047;
          int bh = b * 16 + head;
          uint2 pk; pk.x = lo; pk.y = hi;
          *(uint2*)(vtb + ((size_t)bh * 64 + d) * 2048 + pos) = pk;
        } else {
          bf16_t* dst = (which == 0) ? qb : kb;
          int t = d >> 1;
          for (int r = 0; r < 4; ++r) {
            float v = acc[mt][nt][r] + bias[gn];
            float pn = __shfl_xor(v, 1);  // partner column (d^1), same row
            int gm = gm0 + r;
            int b = gm >> 11, pos = gm & 2047;
            float cc = ropeC[pos * 32 + t], ss = ropeS[pos * 32 + t];
            float o = (d & 1) ? (v * cc + pn * ss) : (v * cc - pn * ss);
            dst[(((size_t)(b * 16 + head)) * 2048 + pos) * 64 + d] = (bf16_t)o;
          }
        }
      } else if constexpr (EPI == EPI_GELU) {
        for (int r = 0; r < 4; ++r) {
          int gm = gm0 + r;
          float v = acc[mt][nt][r] + bias[gn];
          outb[(size_t)gm * Nn + gn] = (bf16_t)fast_gelu(v);
        }
      } else if constexpr (EPI == EPI_PART) {
        float* po = outf + (size_t)blockIdx.y * M * Nn;
        for (int r = 0; r < 4; ++r) {
          int gm = gm0 + r;
          po[(size_t)gm * Nn + gn] = acc[mt][nt][r];
        }
      } else {  // EPI_RESID: out = acc + bias + resid (fp32)
        for (int r = 0; r < 4; ++r) {
          int gm = gm0 + r;
          size_t idx = (size_t)gm * Nn + gn;
          outf[idx] = acc[mt][nt][r] + bias[gn] + resid[idx];
        }
      }
    }
  }
}

// ---------------- Flash attention, 32x32 MFMA, S^T/O^T orientation ----------------
// NO max-subtraction softmax (scores ~±3 vs exp2 range ±126; exact, see r11).
// T14 async-STAGE split on V: V single-buffered in LDS (16 KB); next tile's V
// is loaded to REGISTERS early (latency hides under QK+softmax+PV) and
// ds_written after the post-PV barrier. LDS 64->48 KB => 3 blocks/CU (+50%
// waves). K stays global_load_lds double-buffered.
__global__ __launch_bounds__(256, 3) void attn_kernel(
    const bf16_t* __restrict__ q, const bf16_t* __restrict__ k,
    const bf16_t* __restrict__ vt, bf16_t* __restrict__ o) {
  __shared__ bf16_t lsK[2][128 * 64];   // [key][d], 16B chunks swizzled: slot=c^(row&7)
  __shared__ bf16_t lsV[64 * 128];      // [d][key], slot=c^(row&7); single buffer

  const int tid = threadIdx.x, lane = tid & 63, wave = tid >> 6;
  const int c31 = lane & 31, hi = lane >> 5, h7 = c31 & 7;
  const int bh = blockIdx.y, qt = blockIdx.x;
  const int b = bh >> 4, h = bh & 15;
  const bf16_t* qp = q + (size_t)bh * 2048 * 64;
  const bf16_t* kp = k + (size_t)bh * 2048 * 64;
  const bf16_t* vp = vt + (size_t)bh * 64 * 2048;
  const int qrow0 = qt * 128 + wave * 32;
  const int qrow = qrow0 + c31;

  const float QS = 0.125f * ATTN_LOG2E;
  bf16x8 qb[4];
#pragma unroll
  for (int ks = 0; ks < 4; ++ks) {
    bf16x8 t = *(const bf16x8*)(qp + (size_t)qrow * 64 + ks * 16 + hi * 8);
#pragma unroll
    for (int j = 0; j < 8; ++j) t[j] = (bf16_t)((float)t[j] * QS);
    qb[ks] = t;
  }

  f32x16 oacc[2];
  oacc[0] = 0.f; oacc[1] = 0.f;
  float lstate = 0.f;

  auto stage_k = [&](int kt, int buf) {
    const bf16_t* kg = kp + (size_t)kt * 128 * 64;
    bf16_t* lk = &lsK[buf][0];
#pragma unroll
    for (int i = 0; i < 4; ++i) {
      int s = tid + i * 256;
      int kr = s >> 3, kc = (s & 7) ^ (kr & 7);
      load16(kg + (size_t)kr * 64 + kc * 8, lk + s * 8);
    }
  };
  auto load_v = [&](int kt, bf16x8* vr4) {
#pragma unroll
    for (int i = 0; i < 4; ++i) {
      int s = tid + i * 256;
      int vr = s >> 4, vc = (s & 15) ^ (vr & 7);
      vr4[i] = *(const bf16x8*)(vp + (size_t)vr * 2048 + kt * 128 + vc * 8);
    }
  };
  auto write_v = [&](const bf16x8* vr4) {
#pragma unroll
    for (int i = 0; i < 4; ++i) {
      int s = tid + i * 256;
      *(bf16x8*)(&lsV[s * 8]) = vr4[i];
    }
  };

  bf16x8 vreg[4];
  stage_k(0, 0);
  load_v(0, vreg);
  __syncthreads();                 // K[0] staged; vreg loads drained
  write_v(vreg);
  __syncthreads();                 // V[0] visible

  for (int kt = 0; kt < 16; ++kt) {
    if (kt < 15) {
      stage_k(kt + 1, (kt + 1) & 1);   // async -> other K buffer
      load_v(kt + 1, vreg);            // to regs; hides under compute below
    }
    const bf16_t* lk = &lsK[kt & 1][0];

    f32x16 sacc[4];
    sacc[0] = 0.f; sacc[1] = 0.f; sacc[2] = 0.f; sacc[3] = 0.f;
    __builtin_amdgcn_s_setprio(1);          // T5: favor this wave while MFMA-dense
#pragma unroll
    for (int ks = 0; ks < 4; ++ks) {
      int cs = ((ks * 2 + hi) ^ h7) * 8;
#pragma unroll
      for (int nt = 0; nt < 4; ++nt) {
        bf16x8 kf = *(const bf16x8*)(lk + (nt * 32 + c31) * 64 + cs);
        sacc[nt] = __builtin_amdgcn_mfma_f32_32x32x16_bf16(kf, qb[ks], sacc[nt], 0, 0, 0);
      }
    }
    __builtin_amdgcn_s_setprio(0);

    // p = exp2(s) directly; l accumulates unnormalized
    float rsn[4];
    u32 u[4][4][2];
#pragma unroll
    for (int nt = 0; nt < 4; ++nt) {
      float a0 = 0.f, a1 = 0.f;
#pragma unroll
      for (int t = 0; t < 4; ++t) {
        float p0 = ATTN_EXP(sacc[nt][4 * t + 0]);
        float p1 = ATTN_EXP(sacc[nt][4 * t + 1]);
        float p2 = ATTN_EXP(sacc[nt][4 * t + 2]);
        float p3 = ATTN_EXP(sacc[nt][4 * t + 3]);
        a0 += p0 + p1; a1 += p2 + p3;
        u[nt][t][0] = pk2(p0, p1);
        u[nt][t][1] = pk2(p2, p3);
      }
      rsn[nt] = a0 + a1;
    }
    float rs = (rsn[0] + rsn[1]) + (rsn[2] + rsn[3]);
    rs = pl32_sum(rs);                     // cross-half in 1 permlane + 1 add
    lstate += rs;

    // O^T += V^T * P^T; P-frag cross-half build: 2 permlane32_swap per ks
    __builtin_amdgcn_s_setprio(1);
#pragma unroll
    for (int ks = 0; ks < 8; ++ks) {
      int n = ks >> 1, t0 = (ks & 1) * 2;
      V4U f;
      pl32(u[n][t0][0], u[n][t0 + 1][0], f.w[0], f.w[2]);
      pl32(u[n][t0][1], u[n][t0 + 1][1], f.w[1], f.w[3]);
      bf16x8 pf = f.v;
      int cs = ((ks * 2 + hi) ^ h7) * 8;
#pragma unroll
      for (int dt = 0; dt < 2; ++dt) {
        bf16x8 vf = *(const bf16x8*)(&lsV[(dt * 32 + c31) * 128 + cs]);
        oacc[dt] = __builtin_amdgcn_mfma_f32_32x32x16_bf16(vf, pf, oacc[dt], 0, 0, 0);
      }
    }
    __builtin_amdgcn_s_setprio(0);

    if (kt < 15) {
      __syncthreads();               // PV reads of lsV done; K-stage + vreg drained
      write_v(vreg);                 // V[kt+1] -> LDS
      __syncthreads();               // visible for next iteration
    }
  }

  float inv = 1.0f / lstate;
  bf16_t* orow = o + ((size_t)(b * 2048 + qrow)) * 1024 + h * 64;
#pragma unroll
  for (int dt = 0; dt < 2; ++dt)
#pragma unroll
    for (int t = 0; t < 4; ++t) {
      int d0 = dt * 32 + 8 * t + 4 * hi;
      uint2 pk;
      pk.x = pk2(oacc[dt][4 * t + 0] * inv, oacc[dt][4 * t + 1] * inv);
      pk.y = pk2(oacc[dt][4 * t + 2] * inv, oacc[dt][4 * t + 3] * inv);
      *(uint2*)(orow + d0) = pk;
    }
}

// ---------------- launch ----------------
extern "C" void kernel_launch(void* const* d_in, const int* in_sizes, int n_in,
                              void* d_out, int out_size, void* d_ws, size_t ws_size,
                              hipStream_t stream) {
  const float* x = (const float*)d_in[0];
  const float* ln1_g = (const float*)d_in[1];
  const float* ln1_b = (const float*)d_in[2];
  const float* qkv_w = (const float*)d_in[3];
  const float* qkv_b = (const float*)d_in[4];
  const float* proj_w = (const float*)d_in[5];
  const float* proj_b = (const float*)d_in[6];
  const float* ln2_g = (const float*)d_in[7];
  const float* ln2_b = (const float*)d_in[8];
  const float* fc1_w = (const float*)d_in[9];
  const float* fc1_b = (const float*)d_in[10];
  const float* ffg = (const float*)d_in[11];
  const float* ffb = (const float*)d_in[12];
  const float* fc2_w = (const float*)d_in[13];
  const float* fc2_b = (const float*)d_in[14];
  float* out = (float*)d_out;

  char* ws = (char*)d_ws;
  size_t off = 0;
  auto alloc = [&](size_t n) { char* p = ws + off; off += (n + 255) & ~(size_t)255; return p; };

  bf16_t* qkvT  = (bf16_t*)alloc(3072ull * 1024 * 2);
  bf16_t* projT = (bf16_t*)alloc(1024ull * 1024 * 2);
  bf16_t* fc1T  = (bf16_t*)alloc(4096ull * 1024 * 2);
  bf16_t* fc2T  = (bf16_t*)alloc(1024ull * 4096 * 2);
  float*  ropeC = (float*)alloc(2048ull * 32 * 4);
  float*  ropeS = (float*)alloc(2048ull * 32 * 4);
  bf16_t* hx    = (bf16_t*)alloc(4096ull * 1024 * 2);   // LN1 out; reused for LN2 out
  bf16_t* qbuf  = (bf16_t*)alloc(32ull * 2048 * 64 * 2);
  bf16_t* kbuf  = (bf16_t*)alloc(32ull * 2048 * 64 * 2);
  bf16_t* vtbuf = (bf16_t*)alloc(32ull * 64 * 2048 * 2);
  bf16_t* obuf  = (bf16_t*)alloc(4096ull * 1024 * 2);
  float*  x2    = (float*)alloc(4096ull * 1024 * 4);
  bf16_t* h1    = (bf16_t*)alloc(4096ull * 4096 * 2);
  bf16_t* hln   = (bf16_t*)qbuf;   // alias q..o region (dead after proj GEMM)
  float*  part  = (float*)h1;      // alias h1 (dead after ffn-LN); split-2 partials.
  // NOTE: split-4 was measured WORSE (r13: +8us) — extra 33MB partial writes +
  // 16MB reduce reads ate the latency win. split-2 is the measured optimum.

  // fused: weights -> bf16 transposed (64x64 float4 tiles) + rope table
  prep_kernel<<<3328, 256, 0, stream>>>(qkv_w, proj_w, fc1_w, fc2_w,
                                        qkvT, projT, fc1T, fc2T, ropeC, ropeS);

  // LN1
  ln_kernel<float, 1024><<<4096, 256, 0, stream>>>(x, ln1_g, ln1_b, hx);
  // QKV + RoPE + head scatter; 1D grid, gy=32 m-tiles, 32 K-steps
  gemm_bt<EPI_QKV, 128><<<768, 256, 0, stream>>>(hx, qkvT, 4096, 3072, 1024, 32, 32, qkv_b,
      nullptr, nullptr, nullptr, qbuf, kbuf, vtbuf, ropeC, ropeS);
  // attention
  attn_kernel<<<dim3(16, 32), 256, 0, stream>>>(qbuf, kbuf, vtbuf, obuf);
  // proj + residual -> x2 (fp32); TM=64, gy=64 (known-good round-0 config)
  gemm_bt<EPI_RESID, 64><<<512, 256, 0, stream>>>(obuf, projT, 4096, 1024, 1024, 64, 32,
      proj_b, x, x2, nullptr, nullptr, nullptr, nullptr, nullptr, nullptr);
  // LN2 -> hx (bf16)
  ln_kernel<float, 1024><<<4096, 256, 0, stream>>>(x2, ln2_g, ln2_b, hx);
  // FC1 + fast-GELU -> h1 (bf16); gy=32, 32 K-steps
  gemm_bt<EPI_GELU, 128><<<1024, 256, 0, stream>>>(hx, fc1T, 4096, 4096, 1024, 32, 32, fc1_b,
      nullptr, nullptr, h1, nullptr, nullptr, nullptr, nullptr, nullptr);
  // ffn LN over hidden -> hln (bf16)
  ln_kernel<bf16_t, 4096><<<4096, 256, 0, stream>>>(h1, ffg, ffb, hln);
  // FC2: TM=128, split-K=2 (64 steps each), fp32 partials (alias h1, dead now)
  gemm_bt<EPI_PART, 128><<<dim3(256, 2), 256, 0, stream>>>(hln, fc2T, 4096, 1024, 4096,
      32, 64, nullptr, nullptr, part, nullptr, nullptr, nullptr, nullptr, nullptr, nullptr);
  // combine: out = p0 + p1 + x2 + fc2_b
  reduceN_kernel<2><<<2048, 256, 0, stream>>>(part, x2, fc2_b, out);
}

// Round 15
// 356.602 us; speedup vs baseline: 1.2473x; 1.2473x over previous
//
#include <hip/hip_runtime.h>
#include <hip/hip_bf16.h>
#include <cmath>

typedef __bf16 bf16_t;
typedef __bf16 bf16x8 __attribute__((ext_vector_type(8)));
typedef float f32x4 __attribute__((ext_vector_type(4)));
typedef float f32x16 __attribute__((ext_vector_type(16)));
typedef unsigned short u16;
typedef unsigned int u32;
typedef unsigned int u32x2 __attribute__((ext_vector_type(2)));

// fast exp: raw v_exp_f32 (exp2 domain) when available, else __expf (natural)
#if defined(__has_builtin)
#if __has_builtin(__builtin_amdgcn_exp2f)
#define ATTN_EXP(x) __builtin_amdgcn_exp2f(x)
#define ATTN_LOG2E 1.4426950408889634f
#define HAVE_EXP2 1
#endif
#if __has_builtin(__builtin_amdgcn_permlane32_swap)
#define HAVE_PL32 1
#endif
#if __has_builtin(__builtin_amdgcn_rcpf)
#define FAST_RCP(x) __builtin_amdgcn_rcpf(x)
#endif
#endif
#ifndef ATTN_EXP
#define ATTN_EXP(x) __expf(x)
#define ATTN_LOG2E 1.0f
#endif
#ifndef FAST_RCP
#define FAST_RCP(x) (1.0f / (x))
#endif

// fast GELU, tanh form via exp2-sigmoid (~8 VALU vs ~25-30 for erff;
// |err| ~1e-3, below bf16 output quantization; h1 is LayerNorm'd after).
__device__ __forceinline__ float fast_gelu(float v) {
#ifdef HAVE_EXP2
  float u = v * __builtin_fmaf(0.044715f, v * v, 1.0f);
  float z = __builtin_amdgcn_exp2f(-2.3022163968f * u);
  return v * FAST_RCP(1.0f + z);
#else
  return 0.5f * v * (1.0f + erff(v * 0.70710678118654752f));
#endif
}

// ---------------- async global->LDS (16B per lane) ----------------
__device__ __forceinline__ void load16(const bf16_t* g, bf16_t* l) {
  __builtin_amdgcn_global_load_lds((const __attribute__((address_space(1))) u32*)g,
                                   (__attribute__((address_space(3))) u32*)l, 16, 0, 0);
}

__device__ __forceinline__ u32 pk2(float a, float b) {
  bf16_t x = (bf16_t)a, y = (bf16_t)b;
  u16 ux = __builtin_bit_cast(u16, x), uy = __builtin_bit_cast(u16, y);
  return (u32)ux | ((u32)uy << 16);
}

union V4U { u32 w[4]; bf16x8 v; };

// cross-half (lane^32) exchange of two values in ONE VALU op (T12/m255).
__device__ __forceinline__ void pl32(u32 a, u32 b, u32& out_lo, u32& out_hi) {
#ifdef HAVE_PL32
  u32x2 r = __builtin_amdgcn_permlane32_swap(a, b, false, false);
  out_lo = r[0];
  out_hi = r[1];
#else
  u32 ax = (u32)__shfl_xor((int)a, 32), bx = (u32)__shfl_xor((int)b, 32);
  out_lo = (threadIdx.x & 32) ? bx : a;
  out_hi = (threadIdx.x & 32) ? b : ax;
#endif
}

__device__ __forceinline__ float pl32_sum(float x) {
  u32 lo, hi;
  pl32(__builtin_bit_cast(u32, x), __builtin_bit_cast(u32, x), lo, hi);
  return __builtin_bit_cast(float, lo) + __builtin_bit_cast(float, hi);
}

// ---------------- fused prep: weight transposes (64x64, float4) + rope ----------------
__device__ __forceinline__ void tr64(const float* __restrict__ src, bf16_t* __restrict__ dst,
                                     int Kd, int Nd, int ntile, int ktile, int tid) {
  __shared__ float tile[64][68];
  int n0 = ntile * 64, k0 = ktile * 64;
  int r = tid >> 2, c4 = (tid & 3) * 4;
  const float* sp = src + (size_t)(k0 + r) * Nd + n0;
#pragma unroll
  for (int c = 0; c < 4; ++c)
    *(float4*)&tile[r][c * 16 + c4] = *(const float4*)(sp + c * 16 + c4);
  __syncthreads();
  int n = tid >> 2;
  bf16_t* dp = dst + (size_t)(n0 + n) * Kd + k0;
#pragma unroll
  for (int c = 0; c < 4; ++c) {
    int kk = c * 16 + c4;
    uint2 pk;
    pk.x = pk2(tile[kk + 0][n], tile[kk + 1][n]);
    pk.y = pk2(tile[kk + 2][n], tile[kk + 3][n]);
    *(uint2*)(dp + kk) = pk;
  }
}

__global__ __launch_bounds__(256) void prep_kernel(
    const float* __restrict__ qkv_w, const float* __restrict__ proj_w,
    const float* __restrict__ fc1_w, const float* __restrict__ fc2_w,
    bf16_t* __restrict__ qkvT, bf16_t* __restrict__ projT,
    bf16_t* __restrict__ fc1T, bf16_t* __restrict__ fc2T,
    float* __restrict__ ropeC, float* __restrict__ ropeS) {
  int b = blockIdx.x, tid = threadIdx.x;
  if (b < 768) {
    tr64(qkv_w, qkvT, 1024, 3072, b % 48, b / 48, tid);
  } else if (b < 1024) {
    int r = b - 768; tr64(proj_w, projT, 1024, 1024, r % 16, r / 16, tid);
  } else if (b < 2048) {
    int r = b - 1024; tr64(fc1_w, fc1T, 1024, 4096, r % 64, r / 64, tid);
  } else if (b < 3072) {
    int r = b - 2048; tr64(fc2_w, fc2T, 4096, 1024, r % 16, r / 16, tid);
  } else {
    int idx = (b - 3072) * 256 + tid;
    int pos = idx >> 5, t = idx & 31;
    float e = (float)(2 * t) / 64.0f;
    float inv = powf(10000.0f, -e);
    float a = (float)pos * inv;
    ropeC[idx] = cosf(a);
    ropeS[idx] = sinf(a);
  }
}

// ---------------- LayerNorm: one row per block, width W, vectorized ----------------
template <typename TI, int W>
__global__ __launch_bounds__(256) void ln_kernel(const TI* __restrict__ in,
                                                 const float* __restrict__ g,
                                                 const float* __restrict__ b,
                                                 bf16_t* __restrict__ out) {
  constexpr int CH = (sizeof(TI) == 2) ? 8 : 4;   // 16B chunks
  constexpr int NS = W / (256 * CH);
  int row = blockIdx.x;
  const TI* p = in + (size_t)row * W;
  float vals[NS * CH];
  float s = 0.f, q = 0.f;
#pragma unroll
  for (int sw = 0; sw < NS; ++sw) {
    int base = sw * (256 * CH) + threadIdx.x * CH;
    if constexpr (sizeof(TI) == 2) {
      bf16x8 v = *(const bf16x8*)(p + base);
#pragma unroll
      for (int e = 0; e < 8; ++e) {
        float f = (float)v[e];
        vals[sw * CH + e] = f; s += f; q += f * f;
      }
    } else {
      float4 v = *(const float4*)(p + base);
      float f0 = v.x, f1 = v.y, f2 = v.z, f3 = v.w;
      vals[sw * CH + 0] = f0; vals[sw * CH + 1] = f1;
      vals[sw * CH + 2] = f2; vals[sw * CH + 3] = f3;
      s += (f0 + f1) + (f2 + f3);
      q += (f0 * f0 + f1 * f1) + (f2 * f2 + f3 * f3);
    }
  }
  for (int off = 32; off; off >>= 1) { s += __shfl_xor(s, off); q += __shfl_xor(q, off); }
  __shared__ float red[8];
  int wave = threadIdx.x >> 6, lane = threadIdx.x & 63;
  if (lane == 0) { red[wave] = s; red[4 + wave] = q; }
  __syncthreads();
  s = red[0] + red[1] + red[2] + red[3];
  q = red[4] + red[5] + red[6] + red[7];
  float mu = s * (1.0f / W);
  float var = q * (1.0f / W) - mu * mu;
  float rstd = rsqrtf(var + 1e-5f);
  bf16_t* op = out + (size_t)row * W;
#pragma unroll
  for (int sw = 0; sw < NS; ++sw) {
    int base = sw * (256 * CH) + threadIdx.x * CH;
    float o[CH];
#pragma unroll
    for (int e = 0; e < CH; ++e)
      o[e] = (vals[sw * CH + e] - mu) * rstd * g[base + e] + b[base + e];
    if constexpr (CH == 8) {
      V4U u;
      u.w[0] = pk2(o[0], o[1]); u.w[1] = pk2(o[2], o[3]);
      u.w[2] = pk2(o[4], o[5]); u.w[3] = pk2(o[6], o[7]);
      *(bf16x8*)(op + base) = u.v;
    } else {
      uint2 pk; pk.x = pk2(o[0], o[1]); pk.y = pk2(o[2], o[3]);
      *(uint2*)(op + base) = pk;
    }
  }
}

// ---------------- split-K combine: out = sum(partials) + resid + bias ----------------
template <int NS>
__global__ __launch_bounds__(256) void reduceN_kernel(
    const float* __restrict__ part, const float* __restrict__ resid,
    const float* __restrict__ bias, float* __restrict__ out) {
  const int total4 = (4096 * 1024) / 4;
  const float4* r4 = (const float4*)resid;
  const float4* b4 = (const float4*)bias;
  float4* o4 = (float4*)out;
  for (int i = blockIdx.x * 256 + threadIdx.x; i < total4; i += gridDim.x * 256) {
    float4 a = ((const float4*)part)[i];
#pragma unroll
    for (int s = 1; s < NS; ++s) {
      float4 p = ((const float4*)(part + (size_t)s * 4096 * 1024))[i];
      a.x += p.x; a.y += p.y; a.z += p.z; a.w += p.w;
    }
    float4 r = r4[i], bb = b4[i & 255];
    float4 o;
    o.x = a.x + (r.x + bb.x);
    o.y = a.y + (r.y + bb.y);
    o.z = a.z + (r.z + bb.z);
    o.w = a.w + (r.w + bb.w);
    o4[i] = o;
  }
}

// ---------------- GEMM: C[m][n] = sum_k A[m][k]*Bt[n][k] ----------------
enum { EPI_QKV = 0, EPI_RESID = 1, EPI_GELU = 2, EPI_PART = 3 };

template <int EPI, int TM>
__global__ __launch_bounds__(256, 2) void gemm_bt(
    const bf16_t* __restrict__ A, const bf16_t* __restrict__ Bt, int M, int Nn, int K,
    int gy, int ksteps,
    const float* __restrict__ bias, const float* __restrict__ resid,
    float* __restrict__ outf, bf16_t* __restrict__ outb,
    bf16_t* __restrict__ qb, bf16_t* __restrict__ kb, bf16_t* __restrict__ vtb,
    const float* __restrict__ ropeC, const float* __restrict__ ropeS) {
  constexpr int MT = TM / 32;                 // mfma m-tiles per wave
  __shared__ bf16_t lsA[2][TM * 32];
  __shared__ bf16_t lsB[2][128 * 32];
  const int tid = threadIdx.x;
  const int lane = tid & 63;
  const int wave = tid >> 6;
  const int l16 = lane & 15, quad = lane >> 4;
  const int wm = (wave >> 1) * (TM / 2), wn = (wave & 1) * 64;
  const int bb = blockIdx.x;
  const int m0 = (bb % gy) * TM, n0 = (bb / gy) * 128;
  const int kbase = blockIdx.y * (ksteps << 5);

  f32x4 acc[MT][4];
  for (int i = 0; i < MT; ++i)
    for (int j = 0; j < 4; ++j) acc[i][j] = {0.f, 0.f, 0.f, 0.f};

  auto stage = [&](int kk, int buf) {
    bf16_t* la = &lsA[buf][0];
    bf16_t* lb = &lsB[buf][0];
#pragma unroll
    for (int i = 0; i < TM / 64; ++i) {
      int s = tid + i * 256;
      int row = s >> 2, ch = (s & 3) ^ (row & 3);
      load16(A + (size_t)(m0 + row) * K + kk + ch * 8, la + s * 8);
    }
#pragma unroll
    for (int i = 0; i < 2; ++i) {
      int s = tid + i * 256;
      int row = s >> 2, ch = (s & 3) ^ (row & 3);
      load16(Bt + (size_t)(n0 + row) * K + kk + ch * 8, lb + s * 8);
    }
  };

  stage(kbase, 0);
  for (int ki = 0; ki < ksteps; ++ki) {
    __syncthreads();                        // buf[ki&1] ready
    if (ki + 1 < ksteps) stage(kbase + ((ki + 1) << 5), (ki + 1) & 1);
    const bf16_t* la = &lsA[ki & 1][0];
    const bf16_t* lb = &lsB[ki & 1][0];
    bf16x8 af[MT], bfr[4];
#pragma unroll
    for (int t = 0; t < MT; ++t) {
      int row = wm + t * 16 + l16;
      af[t] = *(const bf16x8*)(la + row * 32 + (quad ^ (row & 3)) * 8);
    }
#pragma unroll
    for (int t = 0; t < 4; ++t) {
      int row = wn + t * 16 + l16;
      bfr[t] = *(const bf16x8*)(lb + row * 32 + (quad ^ (row & 3)) * 8);
    }
#pragma unroll
    for (int mt = 0; mt < MT; ++mt)
#pragma unroll
      for (int nt = 0; nt < 4; ++nt)
        acc[mt][nt] = __builtin_amdgcn_mfma_f32_16x16x32_bf16(af[mt], bfr[nt], acc[mt][nt], 0, 0, 0);
  }

  // epilogue: row = m0+wm+mt*16+quad*4+r, col = n0+wn+nt*16+l16
  for (int mt = 0; mt < MT; ++mt) {
    for (int nt = 0; nt < 4; ++nt) {
      int gn = n0 + wn + nt * 16 + l16;
      int gm0 = m0 + wm + mt * 16 + quad * 4;
      if constexpr (EPI == EPI_QKV) {
        int which = gn >> 10;              // 0=q 1=k 2=v (uniform per nt)
        int hd = gn & 1023, head = hd >> 6, d = hd & 63;
        if (which == 2) {
          u32 lo, hi;
          {
            float v0 = acc[mt][nt][0] + bias[gn];
            float v1 = acc[mt][nt][1] + bias[gn];
            float v2 = acc[mt][nt][2] + bias[gn];
            float v3 = acc[mt][nt][3] + bias[gn];
            lo = pk2(v0, v1);
            hi = pk2(v2, v3);
          }
          int b = gm0 >> 11, pos = gm0 & 2047;
          int bh = b * 16 + head;
          uint2 pk; pk.x = lo; pk.y = hi;
          *(uint2*)(vtb + ((size_t)bh * 64 + d) * 2048 + pos) = pk;
        } else {
          bf16_t* dst = (which == 0) ? qb : kb;
          int t = d >> 1;
          for (int r = 0; r < 4; ++r) {
            float v = acc[mt][nt][r] + bias[gn];
            float pn = __shfl_xor(v, 1);  // partner column (d^1), same row
            int gm = gm0 + r;
            int b = gm >> 11, pos = gm & 2047;
            float cc = ropeC[pos * 32 + t], ss = ropeS[pos * 32 + t];
            float o = (d & 1) ? (v * cc + pn * ss) : (v * cc - pn * ss);
            dst[(((size_t)(b * 16 + head)) * 2048 + pos) * 64 + d] = (bf16_t)o;
          }
        }
      } else if constexpr (EPI == EPI_GELU) {
        for (int r = 0; r < 4; ++r) {
          int gm = gm0 + r;
          float v = acc[mt][nt][r] + bias[gn];
          outb[(size_t)gm * Nn + gn] = (bf16_t)fast_gelu(v);
        }
      } else if constexpr (EPI == EPI_PART) {
        float* po = outf + (size_t)blockIdx.y * M * Nn;
        for (int r = 0; r < 4; ++r) {
          int gm = gm0 + r;
          po[(size_t)gm * Nn + gn] = acc[mt][nt][r];
        }
      } else {  // EPI_RESID: out = acc + bias + resid (fp32)
        for (int r = 0; r < 4; ++r) {
          int gm = gm0 + r;
          size_t idx = (size_t)gm * Nn + gn;
          outf[idx] = acc[mt][nt][r] + bias[gn] + resid[idx];
        }
      }
    }
  }
}

// ---------------- Flash attention, 32x32 MFMA, S^T/O^T orientation ----------------
// NO max-subtraction softmax (scores ~±3 vs exp2 range ±126; exact, see r11).
// T14 async-STAGE split on V: V single-buffered in LDS (16 KB); next tile's V
// is loaded to REGISTERS early (latency hides under QK+softmax+PV) and
// ds_written after the post-PV barrier. LDS 64->48 KB => 3 blocks/CU.
// launch_bounds(256,2): r14 used (256,3) which CAPPED VGPRs at 85 and spilled
// vreg to scratch (+134 MB WRITE_SIZE, attn 2.4x slower). With (256,2) the
// kernel fits ~116 VGPR spill-free and LDS (48 KB) naturally binds occupancy
// at 3 blocks/CU.
__global__ __launch_bounds__(256, 2) void attn_kernel(
    const bf16_t* __restrict__ q, const bf16_t* __restrict__ k,
    const bf16_t* __restrict__ vt, bf16_t* __restrict__ o) {
  __shared__ bf16_t lsK[2][128 * 64];   // [key][d], 16B chunks swizzled: slot=c^(row&7)
  __shared__ bf16_t lsV[64 * 128];      // [d][key], slot=c^(row&7); single buffer

  const int tid = threadIdx.x, lane = tid & 63, wave = tid >> 6;
  const int c31 = lane & 31, hi = lane >> 5, h7 = c31 & 7;
  const int bh = blockIdx.y, qt = blockIdx.x;
  const int b = bh >> 4, h = bh & 15;
  const bf16_t* qp = q + (size_t)bh * 2048 * 64;
  const bf16_t* kp = k + (size_t)bh * 2048 * 64;
  const bf16_t* vp = vt + (size_t)bh * 64 * 2048;
  const int qrow0 = qt * 128 + wave * 32;
  const int qrow = qrow0 + c31;

  const float QS = 0.125f * ATTN_LOG2E;
  bf16x8 qb[4];
#pragma unroll
  for (int ks = 0; ks < 4; ++ks) {
    bf16x8 t = *(const bf16x8*)(qp + (size_t)qrow * 64 + ks * 16 + hi * 8);
#pragma unroll
    for (int j = 0; j < 8; ++j) t[j] = (bf16_t)((float)t[j] * QS);
    qb[ks] = t;
  }

  f32x16 oacc[2];
  oacc[0] = 0.f; oacc[1] = 0.f;
  float lstate = 0.f;

  auto stage_k = [&](int kt, int buf) {
    const bf16_t* kg = kp + (size_t)kt * 128 * 64;
    bf16_t* lk = &lsK[buf][0];
#pragma unroll
    for (int i = 0; i < 4; ++i) {
      int s = tid + i * 256;
      int kr = s >> 3, kc = (s & 7) ^ (kr & 7);
      load16(kg + (size_t)kr * 64 + kc * 8, lk + s * 8);
    }
  };
  auto load_v = [&](int kt, bf16x8* vr4) {
#pragma unroll
    for (int i = 0; i < 4; ++i) {
      int s = tid + i * 256;
      int vr = s >> 4, vc = (s & 15) ^ (vr & 7);
      vr4[i] = *(const bf16x8*)(vp + (size_t)vr * 2048 + kt * 128 + vc * 8);
    }
  };
  auto write_v = [&](const bf16x8* vr4) {
#pragma unroll
    for (int i = 0; i < 4; ++i) {
      int s = tid + i * 256;
      *(bf16x8*)(&lsV[s * 8]) = vr4[i];
    }
  };

  bf16x8 vreg[4];
  stage_k(0, 0);
  load_v(0, vreg);
  __syncthreads();                 // K[0] staged; vreg loads drained
  write_v(vreg);
  __syncthreads();                 // V[0] visible

  for (int kt = 0; kt < 16; ++kt) {
    if (kt < 15) {
      stage_k(kt + 1, (kt + 1) & 1);   // async -> other K buffer
      load_v(kt + 1, vreg);            // to regs; hides under compute below
    }
    const bf16_t* lk = &lsK[kt & 1][0];

    f32x16 sacc[4];
    sacc[0] = 0.f; sacc[1] = 0.f; sacc[2] = 0.f; sacc[3] = 0.f;
    __builtin_amdgcn_s_setprio(1);          // T5: favor this wave while MFMA-dense
#pragma unroll
    for (int ks = 0; ks < 4; ++ks) {
      int cs = ((ks * 2 + hi) ^ h7) * 8;
#pragma unroll
      for (int nt = 0; nt < 4; ++nt) {
        bf16x8 kf = *(const bf16x8*)(lk + (nt * 32 + c31) * 64 + cs);
        sacc[nt] = __builtin_amdgcn_mfma_f32_32x32x16_bf16(kf, qb[ks], sacc[nt], 0, 0, 0);
      }
    }
    __builtin_amdgcn_s_setprio(0);

    // p = exp2(s) directly; l accumulates unnormalized
    float rsn[4];
    u32 u[4][4][2];
#pragma unroll
    for (int nt = 0; nt < 4; ++nt) {
      float a0 = 0.f, a1 = 0.f;
#pragma unroll
      for (int t = 0; t < 4; ++t) {
        float p0 = ATTN_EXP(sacc[nt][4 * t + 0]);
        float p1 = ATTN_EXP(sacc[nt][4 * t + 1]);
        float p2 = ATTN_EXP(sacc[nt][4 * t + 2]);
        float p3 = ATTN_EXP(sacc[nt][4 * t + 3]);
        a0 += p0 + p1; a1 += p2 + p3;
        u[nt][t][0] = pk2(p0, p1);
        u[nt][t][1] = pk2(p2, p3);
      }
      rsn[nt] = a0 + a1;
    }
    float rs = (rsn[0] + rsn[1]) + (rsn[2] + rsn[3]);
    rs = pl32_sum(rs);                     // cross-half in 1 permlane + 1 add
    lstate += rs;

    // O^T += V^T * P^T; P-frag cross-half build: 2 permlane32_swap per ks
    __builtin_amdgcn_s_setprio(1);
#pragma unroll
    for (int ks = 0; ks < 8; ++ks) {
      int n = ks >> 1, t0 = (ks & 1) * 2;
      V4U f;
      pl32(u[n][t0][0], u[n][t0 + 1][0], f.w[0], f.w[2]);
      pl32(u[n][t0][1], u[n][t0 + 1][1], f.w[1], f.w[3]);
      bf16x8 pf = f.v;
      int cs = ((ks * 2 + hi) ^ h7) * 8;
#pragma unroll
      for (int dt = 0; dt < 2; ++dt) {
        bf16x8 vf = *(const bf16x8*)(&lsV[(dt * 32 + c31) * 128 + cs]);
        oacc[dt] = __builtin_amdgcn_mfma_f32_32x32x16_bf16(vf, pf, oacc[dt], 0, 0, 0);
      }
    }
    __builtin_amdgcn_s_setprio(0);

    if (kt < 15) {
      __syncthreads();               // PV reads of lsV done; K-stage + vreg drained
      write_v(vreg);                 // V[kt+1] -> LDS
      __syncthreads();               // visible for next iteration
    }
  }

  float inv = 1.0f / lstate;
  bf16_t* orow = o + ((size_t)(b * 2048 + qrow)) * 1024 + h * 64;
#pragma unroll
  for (int dt = 0; dt < 2; ++dt)
#pragma unroll
    for (int t = 0; t < 4; ++t) {
      int d0 = dt * 32 + 8 * t + 4 * hi;
      uint2 pk;
      pk.x = pk2(oacc[dt][4 * t + 0] * inv, oacc[dt][4 * t + 1] * inv);
      pk.y = pk2(oacc[dt][4 * t + 2] * inv, oacc[dt][4 * t + 3] * inv);
      *(uint2*)(orow + d0) = pk;
    }
}

// ---------------- launch ----------------
extern "C" void kernel_launch(void* const* d_in, const int* in_sizes, int n_in,
                              void* d_out, int out_size, void* d_ws, size_t ws_size,
                              hipStream_t stream) {
  const float* x = (const float*)d_in[0];
  const float* ln1_g = (const float*)d_in[1];
  const float* ln1_b = (const float*)d_in[2];
  const float* qkv_w = (const float*)d_in[3];
  const float* qkv_b = (const float*)d_in[4];
  const float* proj_w = (const float*)d_in[5];
  const float* proj_b = (const float*)d_in[6];
  const float* ln2_g = (const float*)d_in[7];
  const float* ln2_b = (const float*)d_in[8];
  const float* fc1_w = (const float*)d_in[9];
  const float* fc1_b = (const float*)d_in[10];
  const float* ffg = (const float*)d_in[11];
  const float* ffb = (const float*)d_in[12];
  const float* fc2_w = (const float*)d_in[13];
  const float* fc2_b = (const float*)d_in[14];
  float* out = (float*)d_out;

  char* ws = (char*)d_ws;
  size_t off = 0;
  auto alloc = [&](size_t n) { char* p = ws + off; off += (n + 255) & ~(size_t)255; return p; };

  bf16_t* qkvT  = (bf16_t*)alloc(3072ull * 1024 * 2);
  bf16_t* projT = (bf16_t*)alloc(1024ull * 1024 * 2);
  bf16_t* fc1T  = (bf16_t*)alloc(4096ull * 1024 * 2);
  bf16_t* fc2T  = (bf16_t*)alloc(1024ull * 4096 * 2);
  float*  ropeC = (float*)alloc(2048ull * 32 * 4);
  float*  ropeS = (float*)alloc(2048ull * 32 * 4);
  bf16_t* hx    = (bf16_t*)alloc(4096ull * 1024 * 2);   // LN1 out; reused for LN2 out
  bf16_t* qbuf  = (bf16_t*)alloc(32ull * 2048 * 64 * 2);
  bf16_t* kbuf  = (bf16_t*)alloc(32ull * 2048 * 64 * 2);
  bf16_t* vtbuf = (bf16_t*)alloc(32ull * 64 * 2048 * 2);
  bf16_t* obuf  = (bf16_t*)alloc(4096ull * 1024 * 2);
  float*  x2    = (float*)alloc(4096ull * 1024 * 4);
  bf16_t* h1    = (bf16_t*)alloc(4096ull * 4096 * 2);
  bf16_t* hln   = (bf16_t*)qbuf;   // alias q..o region (dead after proj GEMM)
  float*  part  = (float*)h1;      // alias h1 (dead after ffn-LN); split-2 partials.
  // NOTE: split-4 was measured WORSE (r13: +8us) — extra 33MB partial writes +
  // 16MB reduce reads ate the latency win. split-2 is the measured optimum.

  // fused: weights -> bf16 transposed (64x64 float4 tiles) + rope table
  prep_kernel<<<3328, 256, 0, stream>>>(qkv_w, proj_w, fc1_w, fc2_w,
                                        qkvT, projT, fc1T, fc2T, ropeC, ropeS);

  // LN1
  ln_kernel<float, 1024><<<4096, 256, 0, stream>>>(x, ln1_g, ln1_b, hx);
  // QKV + RoPE + head scatter; 1D grid, gy=32 m-tiles, 32 K-steps
  gemm_bt<EPI_QKV, 128><<<768, 256, 0, stream>>>(hx, qkvT, 4096, 3072, 1024, 32, 32, qkv_b,
      nullptr, nullptr, nullptr, qbuf, kbuf, vtbuf, ropeC, ropeS);
  // attention
  attn_kernel<<<dim3(16, 32), 256, 0, stream>>>(qbuf, kbuf, vtbuf, obuf);
  // proj + residual -> x2 (fp32); TM=64, gy=64 (known-good round-0 config)
  gemm_bt<EPI_RESID, 64><<<512, 256, 0, stream>>>(obuf, projT, 4096, 1024, 1024, 64, 32,
      proj_b, x, x2, nullptr, nullptr, nullptr, nullptr, nullptr, nullptr);
  // LN2 -> hx (bf16)
  ln_kernel<float, 1024><<<4096, 256, 0, stream>>>(x2, ln2_g, ln2_b, hx);
  // FC1 + fast-GELU -> h1 (bf16); gy=32, 32 K-steps
  gemm_bt<EPI_GELU, 128><<<1024, 256, 0, stream>>>(hx, fc1T, 4096, 4096, 1024, 32, 32, fc1_b,
      nullptr, nullptr, h1, nullptr, nullptr, nullptr, nullptr, nullptr);
  // ffn LN over hidden -> hln (bf16)
  ln_kernel<bf16_t, 4096><<<4096, 256, 0, stream>>>(h1, ffg, ffb, hln);
  // FC2: TM=128, split-K=2 (64 steps each), fp32 partials (alias h1, dead now)
  gemm_bt<EPI_PART, 128><<<dim3(256, 2), 256, 0, stream>>>(hln, fc2T, 4096, 1024, 4096,
      32, 64, nullptr, nullptr, part, nullptr, nullptr, nullptr, nullptr, nullptr, nullptr);
  // combine: out = p0 + p1 + x2 + fc2_b
  reduceN_kernel<2><<<2048, 256, 0, stream>>>(part, x2, fc2_b, out);
}